// Round 11
// baseline (861.292 us; speedup 1.0000x reference)
//
#include <hip/hip_runtime.h>

// C3 partial conv: x[64,6,256,256] f32, W[16,6,5,5] f32 (sparse table), b[16].
// out[64,16,252,252] f32 = 1.7159*tanh((2/3)*(conv_valid + b)).
//
// Round 14 = Round 13 with the compile fix (OUTS must be static constexpr to
// be referenced in constant expressions; alias removed).
//
// Round 13 rationale: STRAIGHT-LINE pk kernel. The (c,o) schedule is
// compile-time -- the rolled switch (r7/r9/r11/r12) existed only for L1I
// safety, but costs per-case s_load serialization + parking moves; plateau
// 273-330us across 6 rolled variants. With the pk formulation (26 pk-FMA per
// case) the FULLY-UNROLLED kernel is ~19KB -> fits 32KB L1I (r6's 75KB
// disaster was 100-scalar-FMA cases). Straight-line branch-free code lets
// the compiler pipeline scalar weight s_loads across case boundaries (r10's
// goal, zero extra VALU) and statically allocate win/acc.
// vs r12: unroll everything, merge groups (window read once per c: 150 b64
// vs 300), LDS row stride 40->41 v2f (Drow=2 collided 4-way at stride 40:
// 3.49M bank conflicts).
// Weights stay scalar-path, pre-duplicated (w,w) in d_ws (r10 lesson).
// NO launch_bounds min-waves arg (hard VGPR clamp -> scratch, r2/r4).

typedef float v2f __attribute__((ext_vector_type(2)));

__global__ void prep_weights(const float* __restrict__ W, float* __restrict__ Wp) {
    int i = blockIdx.x * 256 + threadIdx.x;   // 0..6143
    if (i < 96 * 64) {
        int oc = i >> 6, k = i & 63;
        Wp[i] = (k < 50) ? W[oc * 25 + (k >> 1)] : 0.0f;   // (w,w) duplicated pairs
    }
}

// acc.x += sum w*win_row0 ; acc.y += sum w*win_row1  -- 25 pk_fma + 1 pk_add
__device__ __forceinline__ void convpk(const v2f* __restrict__ w2,
                                       const v2f (&win)[5][5], v2f& acc) {
    v2f t0 = acc;
    v2f t1 = {0.0f, 0.0f};
    #pragma unroll
    for (int ky = 0; ky < 5; ++ky)
        #pragma unroll
        for (int kx = 0; kx < 5; ++kx) {
            if (ky & 1) t1 = __builtin_elementwise_fma(win[ky][kx], w2[ky * 5 + kx], t1);
            else        t0 = __builtin_elementwise_fma(win[ky][kx], w2[ky * 5 + kx], t0);
        }
    acc = t0 + t1;
}

__global__ __launch_bounds__(256) void c3_partial_conv_kernel(
    const float* __restrict__ x,    // [64,6,256,256]
    const float* __restrict__ Wp,   // [96][64] duplicated-pair weights (d_ws)
    const float* __restrict__ b,    // [16]
    float* __restrict__ out)        // [64,16,252,252]
{
    // Reverse map: input channel c feeds exactly these 10 output channels.
    static constexpr int OUTS[6][10] = {
        {0, 4, 5, 6, 9, 10, 11, 12, 14, 15},
        {0, 1, 5, 6, 7, 10, 11, 12, 13, 15},
        {0, 1, 2, 6, 7, 8, 11, 13, 14, 15},
        {1, 2, 3, 6, 7, 8, 9, 12, 14, 15},
        {2, 3, 4, 7, 8, 9, 10, 12, 13, 15},
        {3, 4, 5, 8, 9, 10, 11, 13, 14, 15},
    };

    // Vertically-paired tile: ldsP[c][pr][col] = (row pr, row pr+1).
    // Row stride 41 v2f: rows differing by 2 no longer bank-alias.
    __shared__ v2f ldsP[6][19][41];   // 37392 B -> 4 blocks/CU

    const int tx  = threadIdx.x;
    const int ty  = threadIdx.y;
    const int tid = ty * 32 + tx;

    const int tileX = blockIdx.x << 5;   // 0..224
    const int tileY = blockIdx.y << 4;   // 0..240
    const int batch = blockIdx.z;

    const float* xb = x + (size_t)batch * 6 * 256 * 256;

    // ---- stage: 6 ch x 19 pair-rows x 9 float4-chunks = 1026 ----
    for (int i = tid; i < 1026; i += 256) {
        int c   = i / 171;            // 19*9
        int rem = i - c * 171;
        int pr  = rem / 9;
        int q   = rem - pr * 9;
        int gr  = tileY + pr;
        int gc0 = tileX + (q << 2);
        float4 a = make_float4(0.f, 0.f, 0.f, 0.f);
        float4 d = make_float4(0.f, 0.f, 0.f, 0.f);
        if (gc0 < 256) {
            const float* rowp = &xb[(c * 256 + gr) * 256 + gc0];
            if (gr < 256)     a = *reinterpret_cast<const float4*>(rowp);
            if (gr + 1 < 256) d = *reinterpret_cast<const float4*>(rowp + 256);
        }
        v2f* dst = &ldsP[c][pr][q << 2];
        dst[0] = v2f{a.x, d.x};
        dst[1] = v2f{a.y, d.y};
        dst[2] = v2f{a.z, d.z};
        dst[3] = v2f{a.w, d.w};
    }
    __syncthreads();

    const int row0 = ty << 1;            // 0..14
    const int ocol = tileX + tx;
    float* ob = out + (size_t)batch * 16 * 252 * 252;
    const bool colok = (ocol < 252);
    const v2f* w2base = reinterpret_cast<const v2f*>(Wp);

    // ---- single merged pass: all 16 accumulators, fully unrolled ----
    v2f accp[16];
    #pragma unroll
    for (int o = 0; o < 16; ++o) { float bv = b[o]; accp[o] = v2f{bv, bv}; }

    #pragma unroll
    for (int c = 0; c < 6; ++c) {
        v2f win[5][5];
        const v2f* cb = &ldsP[c][row0][tx];
        #pragma unroll
        for (int ky = 0; ky < 5; ++ky)
            #pragma unroll
            for (int kx = 0; kx < 5; ++kx)
                win[ky][kx] = cb[ky * 41 + kx];   // aligned ds_read_b64

        #pragma unroll
        for (int oi = 0; oi < 10; ++oi) {
            const int o = OUTS[c][oi];           // compile-time constant
            convpk(w2base + (o * 6 + c) * 32, win, accp[o]);
        }
    }

    // ---- epilogue ----
    if (colok) {
        #pragma unroll
        for (int o = 0; o < 16; ++o) {
            float av[2] = {accp[o].x, accp[o].y};
            #pragma unroll
            for (int dy = 0; dy < 2; ++dy) {
                int orow = tileY + row0 + dy;
                if (orow < 252) {
                    float z = av[dy] * (2.0f / 3.0f);
                    float e = __expf(2.0f * z);
                    float rr = __builtin_amdgcn_rcpf(e + 1.0f);
                    ob[(o * 252 + orow) * 252 + ocol] = 1.7159f * (1.0f - 2.0f * rr);
                }
            }
        }
    }
}

extern "C" void kernel_launch(void* const* d_in, const int* in_sizes, int n_in,
                              void* d_out, int out_size, void* d_ws, size_t ws_size,
                              hipStream_t stream) {
    const float* x = (const float*)d_in[0];
    const float* W = (const float*)d_in[1];
    const float* b = (const float*)d_in[2];
    float* out = (float*)d_out;
    float* Wp  = (float*)d_ws;     // needs 96*64*4 = 24576 B

    hipLaunchKernelGGL(prep_weights, dim3(24), dim3(256), 0, stream, W, Wp);

    dim3 grid(8, 16, 64);
    dim3 block(32, 8);
    hipLaunchKernelGGL(c3_partial_conv_kernel, grid, block, 0, stream, x, Wp, b, out);
}

// Round 12
// 484.182 us; speedup vs baseline: 1.7789x; 1.7789x over previous
//
#include <hip/hip_runtime.h>

// C3 partial conv: x[64,6,256,256] f32, W[16,6,5,5] f32 (sparse table), b[16].
// out[64,16,252,252] f32 = 1.7159*tanh((2/3)*(conv_valid + b)).
//
// Round 15: WAVE-LEVEL channel split. Rolled variants plateau 273-330us
// (per-case s_load serialization + AGPR-parking moves); straight-line dies
// on L1I (r6, 75KB) or live-set blowup (r14, VGPR=164 @ 16ch merged).
// Fix both at once: threadIdx.z in {0,1} selects channel group 0..7 / 8..15.
// z is wave-uniform (block 32x8x2; wave = one z-slice) -> each wave runs ONE
// straight-line compile-time half: no switch, no branch serialization,
// ~7KB code/path (pk form, 14KB total << L1I), ~70-reg live set, half-length
// VALU stream/wave. sched_barrier(0) per channel blocks the cross-c hoisting
// that blew up r14. LDS tile staged once, shared by both halves.
// pk layout + convpk + prep_weights reused VERBATIM from r12 (verified).
// Weights scalar-path, pre-duplicated (w,w) in d_ws (r10 lesson).
// NO launch_bounds min-waves arg (hard VGPR clamp -> scratch, r2/r4).

typedef float v2f __attribute__((ext_vector_type(2)));

// per-half reverse maps; GO entries are LOCAL o (0..7), channel = 8h + o
static constexpr int GN[2][6] = {{4, 5, 5, 5, 4, 3}, {6, 5, 5, 5, 6, 7}};
static constexpr int GO[2][6][7] = {
    {{0, 4, 5, 6, 0, 0, 0},     // c=0: outs 0,4,5,6
     {0, 1, 5, 6, 7, 0, 0},     // c=1
     {0, 1, 2, 6, 7, 0, 0},     // c=2
     {1, 2, 3, 6, 7, 0, 0},     // c=3
     {2, 3, 4, 7, 0, 0, 0},     // c=4
     {3, 4, 5, 0, 0, 0, 0}},    // c=5
    {{1, 2, 3, 4, 6, 7, 0},     // c=0: outs 9,10,11,12,14,15
     {2, 3, 4, 5, 7, 0, 0},     // c=1: 10,11,12,13,15
     {0, 3, 5, 6, 7, 0, 0},     // c=2: 8,11,13,14,15
     {0, 1, 4, 6, 7, 0, 0},     // c=3: 8,9,12,14,15
     {0, 1, 2, 4, 5, 7, 0},     // c=4: 8,9,10,12,13,15
     {0, 1, 2, 3, 5, 6, 7}}};   // c=5: 8,9,10,11,13,14,15

__global__ void prep_weights(const float* __restrict__ W, float* __restrict__ Wp) {
    int i = blockIdx.x * 256 + threadIdx.x;   // 0..6143
    if (i < 96 * 64) {
        int oc = i >> 6, k = i & 63;
        Wp[i] = (k < 50) ? W[oc * 25 + (k >> 1)] : 0.0f;   // (w,w) duplicated pairs
    }
}

// acc.x += sum w*win_row0 ; acc.y += sum w*win_row1  -- 25 pk_fma + 1 pk_add
__device__ __forceinline__ void convpk(const v2f* __restrict__ w2,
                                       const v2f (&win)[5][5], v2f& acc) {
    v2f t0 = acc;
    v2f t1 = {0.0f, 0.0f};
    #pragma unroll
    for (int ky = 0; ky < 5; ++ky)
        #pragma unroll
        for (int kx = 0; kx < 5; ++kx) {
            if (ky & 1) t1 = __builtin_elementwise_fma(win[ky][kx], w2[ky * 5 + kx], t1);
            else        t0 = __builtin_elementwise_fma(win[ky][kx], w2[ky * 5 + kx], t0);
        }
    acc = t0 + t1;
}

__global__ __launch_bounds__(512) void c3_partial_conv_kernel(
    const float* __restrict__ x,    // [64,6,256,256]
    const float* __restrict__ Wp,   // [96][64] duplicated-pair weights (d_ws)
    const float* __restrict__ b,    // [16]
    float* __restrict__ out)        // [64,16,252,252]
{
    // Vertically-paired tile: ldsP[c][pr][col] = (row pr, row pr+1).
    __shared__ v2f ldsP[6][19][41];   // 37392 B -> 4 blocks/CU (thread cap also 4)

    const int tx  = threadIdx.x;      // 0..31 -> output col
    const int ty  = threadIdx.y;      // 0..7  -> output row pair
    const int h   = threadIdx.z;      // 0..1  -> channel half (WAVE-uniform)
    const int tid = (h * 8 + ty) * 32 + tx;   // 0..511

    const int tileX = blockIdx.x << 5;   // 0..224
    const int tileY = blockIdx.y << 4;   // 0..240
    const int batch = blockIdx.z;

    const float* xb = x + (size_t)batch * 6 * 256 * 256;

    // ---- stage: 6 ch x 19 pair-rows x 9 float4-chunks = 1026 ----
    for (int i = tid; i < 1026; i += 512) {
        int c   = i / 171;            // 19*9
        int rem = i - c * 171;
        int pr  = rem / 9;
        int q   = rem - pr * 9;
        int gr  = tileY + pr;
        int gc0 = tileX + (q << 2);
        float4 a = make_float4(0.f, 0.f, 0.f, 0.f);
        float4 d = make_float4(0.f, 0.f, 0.f, 0.f);
        if (gc0 < 256) {
            const float* rowp = &xb[(c * 256 + gr) * 256 + gc0];
            if (gr < 256)     a = *reinterpret_cast<const float4*>(rowp);
            if (gr + 1 < 256) d = *reinterpret_cast<const float4*>(rowp + 256);
        }
        v2f* dst = &ldsP[c][pr][q << 2];
        dst[0] = v2f{a.x, d.x};
        dst[1] = v2f{a.y, d.y};
        dst[2] = v2f{a.z, d.z};
        dst[3] = v2f{a.w, d.w};
    }
    __syncthreads();

    const int row0 = ty << 1;            // 0..14
    const int ocol = tileX + tx;
    float* ob = out + (size_t)batch * 16 * 252 * 252;
    const bool colok = (ocol < 252);
    const v2f* w2base = reinterpret_cast<const v2f*>(Wp);

    // ---- this wave's half: 8 accumulators, straight-line ----
    v2f accp[8];
    #pragma unroll
    for (int o = 0; o < 8; ++o) { float bv = b[h * 8 + o]; accp[o] = v2f{bv, bv}; }

    #pragma unroll
    for (int c = 0; c < 6; ++c) {
        v2f win[5][5];
        const v2f* cb = &ldsP[c][row0][tx];
        #pragma unroll
        for (int ky = 0; ky < 5; ++ky)
            #pragma unroll
            for (int kx = 0; kx < 5; ++kx)
                win[ky][kx] = cb[ky * 41 + kx];   // aligned ds_read_b64

        if (h == 0) {
            #pragma unroll
            for (int oi = 0; oi < GN[0][c]; ++oi) {
                const int o = GO[0][c][oi];              // compile-time
                convpk(w2base + (o * 6 + c) * 32, win, accp[o]);
            }
        } else {
            #pragma unroll
            for (int oi = 0; oi < GN[1][c]; ++oi) {
                const int o = GO[1][c][oi];              // compile-time
                convpk(w2base + ((8 + o) * 6 + c) * 32, win, accp[o]);
            }
        }
        // stop cross-channel hoisting (r14's live-set blowup mechanism)
        __builtin_amdgcn_sched_barrier(0);
    }

    // ---- epilogue: this half's 8 channels ----
    if (colok) {
        #pragma unroll
        for (int o = 0; o < 8; ++o) {
            float av[2] = {accp[o].x, accp[o].y};
            #pragma unroll
            for (int dy = 0; dy < 2; ++dy) {
                int orow = tileY + row0 + dy;
                if (orow < 252) {
                    float z = av[dy] * (2.0f / 3.0f);
                    float e = __expf(2.0f * z);
                    float rr = __builtin_amdgcn_rcpf(e + 1.0f);
                    ob[((h * 8 + o) * 252 + orow) * 252 + ocol] = 1.7159f * (1.0f - 2.0f * rr);
                }
            }
        }
    }
}

extern "C" void kernel_launch(void* const* d_in, const int* in_sizes, int n_in,
                              void* d_out, int out_size, void* d_ws, size_t ws_size,
                              hipStream_t stream) {
    const float* x = (const float*)d_in[0];
    const float* W = (const float*)d_in[1];
    const float* b = (const float*)d_in[2];
    float* out = (float*)d_out;
    float* Wp  = (float*)d_ws;     // needs 96*64*4 = 24576 B

    hipLaunchKernelGGL(prep_weights, dim3(24), dim3(256), 0, stream, W, Wp);

    dim3 grid(8, 16, 64);          // 8 col-tiles x 16 row-tiles x 64 batches
    dim3 block(32, 8, 2);          // z = channel half (wave-uniform)
    hipLaunchKernelGGL(c3_partial_conv_kernel, grid, block, 0, stream, x, Wp, b, out);
}